// Round 1
// baseline (2060.193 us; speedup 1.0000x reference)
//
#include <hip/hip_runtime.h>

#define BSZ 8
#define DIM 512
#define TSZ 2048
#define STEPS 12
#define NNEG 10
#define COPIES 11
#define TCH 16

// ws layout:
//   y_t: [BSZ][TSZ][DIM] f32 at byte offset 0                (33,554,432 B)
//   Wt : [STEPS][DIM][DIM] f32 at byte offset 33,554,432     (12,582,912 B)
// out layout:
//   predictions: 2,155,824 f32 (segments i=0..11, each (2047-i)*88)
//   labels     : 195,984 zeros

__global__ __launch_bounds__(1024) void transpose_y_kernel(const float* __restrict__ y,
                                                           float* __restrict__ yt) {
    __shared__ float tile[32][33];
    const int bb = blockIdx.z;
    const int d0 = blockIdx.y * 32;
    const int t0 = blockIdx.x * 32;
    const int tx = threadIdx.x, ty = threadIdx.y;
    tile[ty][tx] = y[((size_t)(bb * DIM + d0 + ty)) * TSZ + t0 + tx];
    __syncthreads();
    yt[((size_t)(bb * TSZ + t0 + ty)) * DIM + d0 + tx] = tile[tx][ty];
}

__global__ __launch_bounds__(256) void transpose_w_kernel(const float* __restrict__ W,
                                                          float* __restrict__ Wt) {
    __shared__ float buf[DIM * STEPS];  // 24 KB
    const int d = blockIdx.x;
    for (int idx = threadIdx.x; idx < DIM * STEPS; idx += 256)
        buf[idx] = W[(size_t)d * DIM * STEPS + idx];
    __syncthreads();
    for (int idx = threadIdx.x; idx < DIM * STEPS; idx += 256) {
        const int i = idx >> 9;    // step
        const int c = idx & 511;   // out-channel
        Wt[((size_t)i * DIM + d) * DIM + c] = buf[c * STEPS + i];
    }
}

__global__ __launch_bounds__(256) void fused_kernel(const float* __restrict__ x,
                                                    const float* __restrict__ yt,
                                                    const float* __restrict__ Wt,
                                                    const float* __restrict__ bias,
                                                    const int* __restrict__ neg,
                                                    float* __restrict__ out) {
    __shared__ float xs[DIM][TCH];   // 32 KB: x[bb, d, t0:t0+16]
    __shared__ float xps[TCH][DIM];  // 32 KB: xp[t][c] for this (bb, i, chunk)
    const int tchunk = blockIdx.x;
    const int i = blockIdx.y;
    const int bb = blockIdx.z;
    const int t0 = tchunk * TCH;
    const int tid = threadIdx.x;

    // ---- stage x tile (coalesced float4) ----
    #pragma unroll
    for (int k = 0; k < 8; ++k) {
        const int l = tid + k * 256;      // 0..2047
        const int d = l >> 2, tq = l & 3;
        const float4 v = *(const float4*)(&x[((size_t)(bb * DIM + d)) * TSZ + t0 + tq * 4]);
        *(float4*)(&xs[d][tq * 4]) = v;
    }
    __syncthreads();

    // ---- step B: xp[t][c] = sum_d Wt[i][d][c] * xs[d][t] + b[c] ----
    const int tc = tid & 3;    // t-group (4 t each)
    const int cc = tid >> 2;   // c-group (8 c each), 64 groups
    const float* Wrow = Wt + (size_t)i * DIM * DIM + cc * 8;
    float acc[8][4];
    #pragma unroll
    for (int m = 0; m < 8; ++m)
        #pragma unroll
        for (int q = 0; q < 4; ++q) acc[m][q] = 0.f;

    #pragma unroll 4
    for (int d = 0; d < DIM; ++d) {
        const float4 w0 = *(const float4*)(Wrow + (size_t)d * DIM);
        const float4 w1 = *(const float4*)(Wrow + (size_t)d * DIM + 4);
        const float4 xv = *(const float4*)(&xs[d][tc * 4]);
        const float wv[8] = {w0.x, w0.y, w0.z, w0.w, w1.x, w1.y, w1.z, w1.w};
        const float xvv[4] = {xv.x, xv.y, xv.z, xv.w};
        #pragma unroll
        for (int m = 0; m < 8; ++m)
            #pragma unroll
            for (int q = 0; q < 4; ++q)
                acc[m][q] = fmaf(wv[m], xvv[q], acc[m][q]);
    }

    float bv[8];
    #pragma unroll
    for (int m = 0; m < 8; ++m) bv[m] = bias[cc * 8 + m];

    #pragma unroll
    for (int q = 0; q < 4; ++q) {
        const float4 o0 = make_float4(acc[0][q] + bv[0], acc[1][q] + bv[1],
                                      acc[2][q] + bv[2], acc[3][q] + bv[3]);
        const float4 o1 = make_float4(acc[4][q] + bv[4], acc[5][q] + bv[5],
                                      acc[6][q] + bv[6], acc[7][q] + bv[7]);
        *(float4*)(&xps[tc * 4 + q][cc * 8]) = o0;
        *(float4*)(&xps[tc * 4 + q][cc * 8 + 4]) = o1;
    }
    __syncthreads();

    // ---- step C: dots against targets ----
    const int w = tid >> 6, lane = tid & 63;
    const int off = i + 1;
    const size_t segoff = (size_t)88 * ((size_t)2047 * i - (size_t)(i * (i - 1) / 2));
    #pragma unroll 1
    for (int jj = 0; jj < 44; ++jj) {
        const int j = w * 44 + jj;            // 0..175
        const int tl = j / 11;
        const int n = j - tl * 11;
        const int t = t0 + tl;
        if (t < TSZ - off) {
            const int tau = t + off;
            const int col = (n == 0) ? (bb * TSZ + tau)
                                     : neg[bb * (NNEG * TSZ) + (n - 1) * TSZ + tau];
            const float* tv = yt + (size_t)col * DIM + lane * 8;
            const float4 a0 = *(const float4*)(tv);
            const float4 a1 = *(const float4*)(tv + 4);
            const float4 p0 = *(const float4*)(&xps[tl][lane * 8]);
            const float4 p1 = *(const float4*)(&xps[tl][lane * 8 + 4]);
            float s = a0.x * p0.x + a0.y * p0.y + a0.z * p0.z + a0.w * p0.w +
                      a1.x * p1.x + a1.y * p1.y + a1.z * p1.z + a1.w * p1.w;
            #pragma unroll
            for (int m = 32; m >= 1; m >>= 1) s += __shfl_xor(s, m, 64);
            if (lane == 0)
                out[segoff + ((size_t)t * BSZ + bb) * COPIES + n] = s;
        }
    }
}

__global__ __launch_bounds__(256) void labels_kernel(float* __restrict__ out) {
    const int idx = blockIdx.x * 256 + threadIdx.x;
    if (idx < 195984) out[2155824 + idx] = 0.0f;
}

extern "C" void kernel_launch(void* const* d_in, const int* in_sizes, int n_in,
                              void* d_out, int out_size, void* d_ws, size_t ws_size,
                              hipStream_t stream) {
    const float* x = (const float*)d_in[0];
    const float* y = (const float*)d_in[1];
    const float* W = (const float*)d_in[2];
    const float* b = (const float*)d_in[3];
    const int* neg = (const int*)d_in[4];
    float* out = (float*)d_out;
    float* yt = (float*)d_ws;
    float* Wt = (float*)((char*)d_ws + (size_t)BSZ * TSZ * DIM * 4);

    transpose_y_kernel<<<dim3(TSZ / 32, DIM / 32, BSZ), dim3(32, 32), 0, stream>>>(y, yt);
    transpose_w_kernel<<<dim3(DIM), dim3(256), 0, stream>>>(W, Wt);
    fused_kernel<<<dim3(TSZ / TCH, STEPS, BSZ), dim3(256), 0, stream>>>(x, yt, Wt, b, neg, out);
    labels_kernel<<<dim3(766), dim3(256), 0, stream>>>(out);
}

// Round 2
// 971.830 us; speedup vs baseline: 2.1199x; 2.1199x over previous
//
#include <hip/hip_runtime.h>

#define BSZ 8
#define DIM 512
#define TSZ 2048
#define STEPS 12
#define NNEG 10
#define COPIES 11
#define TCH 32

typedef unsigned short ushortT;
typedef unsigned int uintT;
typedef __attribute__((ext_vector_type(8))) short short8v;
typedef __attribute__((ext_vector_type(4))) float f32x4;

// ws layout (bytes):
//   xt : [BSZ][TSZ][DIM] bf16 @ 0           (16,777,216)
//   yt : [BSZ][TSZ][DIM] bf16 @ 16,777,216  (16,777,216)
//   Wco: [STEPS][DIM c][DIM d] bf16 @ 33,554,432 (6,291,456)
// out: predictions 2,155,824 f32, then labels 195,984 f32 zeros.

__device__ __forceinline__ ushortT f2bf(float f) {
    uintT u = __builtin_bit_cast(uintT, f);
    u = (u + 0x7fffu + ((u >> 16) & 1u)) >> 16;
    return (ushortT)u;
}

__device__ __forceinline__ float bfdot2(uintT a, uintT p, float s) {
    const float alo = __builtin_bit_cast(float, a << 16);
    const float plo = __builtin_bit_cast(float, p << 16);
    const float ahi = __builtin_bit_cast(float, a & 0xffff0000u);
    const float phi = __builtin_bit_cast(float, p & 0xffff0000u);
    return fmaf(ahi, phi, fmaf(alo, plo, s));
}

// x,y f32 [b][d][t] -> bf16 [b][t][d]
__global__ __launch_bounds__(1024) void transpose_xy_kernel(const float* __restrict__ x,
                                                            const float* __restrict__ y,
                                                            ushortT* __restrict__ xt,
                                                            ushortT* __restrict__ yt) {
    __shared__ float tile[32][33];
    const int z = blockIdx.z;
    const int bb = z & 7;
    const float* src = (z < 8) ? x : y;
    ushortT* dst = (z < 8) ? xt : yt;
    const int d0 = blockIdx.y * 32;
    const int t0 = blockIdx.x * 32;
    const int tx = threadIdx.x, ty = threadIdx.y;
    tile[ty][tx] = src[((size_t)(bb * DIM + d0 + ty)) * TSZ + t0 + tx];
    __syncthreads();
    dst[((size_t)(bb * TSZ + t0 + ty)) * DIM + d0 + tx] = f2bf(tile[tx][ty]);
}

// W f32 [d][c][i] -> bf16 Wco [i][c][d]
__global__ __launch_bounds__(256) void transpose_w_kernel(const float* __restrict__ W,
                                                          ushortT* __restrict__ Wco) {
    __shared__ float buf[DIM * STEPS];  // 24 KB
    const int d = blockIdx.x;
    for (int idx = threadIdx.x; idx < DIM * STEPS; idx += 256)
        buf[idx] = W[(size_t)d * DIM * STEPS + idx];
    __syncthreads();
    for (int idx = threadIdx.x; idx < DIM * STEPS; idx += 256) {
        const int i = idx >> 9;    // step
        const int c = idx & 511;   // out-channel
        Wco[((size_t)i * DIM + c) * DIM + d] = f2bf(buf[c * STEPS + i]);
    }
}

__global__ __launch_bounds__(256) void fused_kernel(const ushortT* __restrict__ xt,
                                                    const ushortT* __restrict__ yt,
                                                    const ushortT* __restrict__ Wco,
                                                    const float* __restrict__ bias,
                                                    const int* __restrict__ neg,
                                                    float* __restrict__ out) {
    __shared__ ushortT xs[TCH][DIM + 8];   // 33,280 B  (x tile, [t][d])
    __shared__ ushortT xps[TCH][DIM + 8];  // 33,280 B  (xp tile, [t][c], bf16)
    const int tchunk = blockIdx.x;
    const int i = blockIdx.y;
    const int bb = blockIdx.z;
    const int t0 = tchunk * TCH;
    const int tid = threadIdx.x;
    const int lane = tid & 63;
    const int w = tid >> 6;        // wave 0..3
    const int r16 = lane & 15;
    const int g = lane >> 4;       // k-group 0..3

    // ---- stage x tile: 32 rows x 1KB, one row per wave per pass ----
    #pragma unroll
    for (int p = 0; p < 8; ++p) {
        const int row = p * 4 + w;
        const uint4 v = *(const uint4*)(xt + ((size_t)bb * TSZ + t0 + row) * DIM + lane * 8);
        *(uint4*)(&xs[row][lane * 8]) = v;
    }
    __syncthreads();

    // ---- step B: MFMA GEMM  xp[o][t] = sum_d Wco[i][o][d] * xs[t][d] ----
    f32x4 acc[8][2] = {};
    const ushortT* wbase = Wco + (size_t)i * DIM * DIM + (size_t)(w * 128 + r16) * DIM + 8 * g;
    for (int kt = 0; kt < 16; ++kt) {
        const int k0 = kt * 32;
        const short8v b0 = *(const short8v*)(&xs[r16][k0 + 8 * g]);
        const short8v b1 = *(const short8v*)(&xs[16 + r16][k0 + 8 * g]);
        #pragma unroll
        for (int m = 0; m < 8; ++m) {
            const short8v af = *(const short8v*)(wbase + (size_t)m * 16 * DIM + k0);
            acc[m][0] = __builtin_amdgcn_mfma_f32_16x16x32_bf16(af, b0, acc[m][0], 0, 0, 0);
            acc[m][1] = __builtin_amdgcn_mfma_f32_16x16x32_bf16(af, b1, acc[m][1], 0, 0, 0);
        }
    }

    // ---- epilogue: + bias, cast bf16, write xps[t][c] ----
    #pragma unroll
    for (int m = 0; m < 8; ++m) {
        const int c0 = w * 128 + m * 16 + 4 * g;
        const float4 bv = *(const float4*)(bias + c0);
        #pragma unroll
        for (int tt = 0; tt < 2; ++tt) {
            const f32x4 v = acc[m][tt];
            ushort4 h;
            h.x = f2bf(v.x + bv.x);
            h.y = f2bf(v.y + bv.y);
            h.z = f2bf(v.z + bv.z);
            h.w = f2bf(v.w + bv.w);
            *(ushort4*)(&xps[tt * 16 + r16][c0]) = h;
        }
    }
    __syncthreads();

    // ---- step C: dots against targets ----
    const int off = i + 1;
    const size_t segoff = 88ull * (2047ull * (size_t)i - (size_t)(i * (i - 1)) / 2);
    #pragma unroll 4
    for (int jj = 0; jj < 88; ++jj) {
        const int j = w * 88 + jj;             // 0..351
        const int tl = j / 11;
        const int n = j - tl * 11;
        const int t = t0 + tl;
        if (t < TSZ - off) {
            const int tau = t + off;
            const int col = (n == 0) ? (bb * TSZ + tau)
                                     : neg[bb * (NNEG * TSZ) + (n - 1) * TSZ + tau];
            const uint4 a = *(const uint4*)(yt + (size_t)col * DIM + lane * 8);
            const uint4 p = *(const uint4*)(&xps[tl][lane * 8]);
            float s = 0.f;
            s = bfdot2(a.x, p.x, s);
            s = bfdot2(a.y, p.y, s);
            s = bfdot2(a.z, p.z, s);
            s = bfdot2(a.w, p.w, s);
            #pragma unroll
            for (int m = 32; m >= 1; m >>= 1) s += __shfl_xor(s, m, 64);
            if (lane == 0)
                out[segoff + ((size_t)t * BSZ + bb) * COPIES + n] = s;
        }
    }
}

__global__ __launch_bounds__(256) void labels_kernel(float* __restrict__ out) {
    const int idx = blockIdx.x * 256 + threadIdx.x;
    if (idx < 195984) out[2155824 + idx] = 0.0f;
}

extern "C" void kernel_launch(void* const* d_in, const int* in_sizes, int n_in,
                              void* d_out, int out_size, void* d_ws, size_t ws_size,
                              hipStream_t stream) {
    const float* x = (const float*)d_in[0];
    const float* y = (const float*)d_in[1];
    const float* W = (const float*)d_in[2];
    const float* b = (const float*)d_in[3];
    const int* neg = (const int*)d_in[4];
    float* out = (float*)d_out;
    ushortT* xt = (ushortT*)d_ws;
    ushortT* yt = (ushortT*)((char*)d_ws + 16777216);
    ushortT* Wco = (ushortT*)((char*)d_ws + 33554432);

    transpose_xy_kernel<<<dim3(TSZ / 32, DIM / 32, 16), dim3(32, 32), 0, stream>>>(x, y, xt, yt);
    transpose_w_kernel<<<dim3(DIM), dim3(256), 0, stream>>>(W, Wco);
    fused_kernel<<<dim3(TSZ / TCH, STEPS, BSZ), dim3(256), 0, stream>>>(xt, yt, Wco, b, neg, out);
    labels_kernel<<<dim3(766), dim3(256), 0, stream>>>(out);
}

// Round 3
// 467.144 us; speedup vs baseline: 4.4102x; 2.0804x over previous
//
#include <hip/hip_runtime.h>

#define BSZ 8
#define DIM 512
#define TSZ 2048
#define STEPS 12
#define NNEG 10
#define COPIES 11
#define TCH 64

typedef unsigned short ushortT;
typedef unsigned int uintT;
typedef __attribute__((ext_vector_type(8))) short short8v;
typedef __attribute__((ext_vector_type(4))) float f32x4;

// ws layout (bytes):
//   xt : [BSZ][TSZ][DIM] bf16 @ 0           (16,777,216)
//   yt : [BSZ][TSZ][DIM] bf16 @ 16,777,216  (16,777,216)
//   Wco: [STEPS][DIM c][DIM d] bf16 @ 33,554,432 (6,291,456)
// out: predictions 2,155,824 f32, then labels 195,984 f32 zeros.

__device__ __forceinline__ ushortT f2bf(float f) {
    uintT u = __builtin_bit_cast(uintT, f);
    u = (u + 0x7fffu + ((u >> 16) & 1u)) >> 16;
    return (ushortT)u;
}

// x,y f32 [b][d][t] -> bf16 [b][t][d]
__global__ __launch_bounds__(1024) void transpose_xy_kernel(const float* __restrict__ x,
                                                            const float* __restrict__ y,
                                                            ushortT* __restrict__ xt,
                                                            ushortT* __restrict__ yt) {
    __shared__ float tile[32][33];
    const int z = blockIdx.z;
    const int bb = z & 7;
    const float* src = (z < 8) ? x : y;
    ushortT* dst = (z < 8) ? xt : yt;
    const int d0 = blockIdx.y * 32;
    const int t0 = blockIdx.x * 32;
    const int tx = threadIdx.x, ty = threadIdx.y;
    tile[ty][tx] = src[((size_t)(bb * DIM + d0 + ty)) * TSZ + t0 + tx];
    __syncthreads();
    dst[((size_t)(bb * TSZ + t0 + ty)) * DIM + d0 + tx] = f2bf(tile[tx][ty]);
}

// W f32 [d][c][i] -> bf16 Wco [i][c][d]
__global__ __launch_bounds__(256) void transpose_w_kernel(const float* __restrict__ W,
                                                          ushortT* __restrict__ Wco) {
    __shared__ float buf[DIM * STEPS];  // 24 KB
    const int d = blockIdx.x;
    for (int idx = threadIdx.x; idx < DIM * STEPS; idx += 256)
        buf[idx] = W[(size_t)d * DIM * STEPS + idx];
    __syncthreads();
    for (int idx = threadIdx.x; idx < DIM * STEPS; idx += 256) {
        const int i = idx >> 9;
        const int c = idx & 511;
        Wco[((size_t)i * DIM + c) * DIM + d] = f2bf(buf[c * STEPS + i]);
    }
}

__global__ __launch_bounds__(512, 4) void fused_kernel(const ushortT* __restrict__ xt,
                                                       const ushortT* __restrict__ yt,
                                                       const ushortT* __restrict__ Wco,
                                                       const float* __restrict__ bias,
                                                       const int* __restrict__ neg,
                                                       float* __restrict__ out) {
    // 64 KB buffer: x-tile [64 t][512 d] bf16 during GEMM, then reused as
    // xp-tile [64 t][512 c] bf16 for step C. Rows are 1024 B; 16 B chunks are
    // XOR-swizzled: physical_chunk = logical_chunk ^ (row & 7).
    __shared__ ushortT xs[TCH * DIM];
    const int tchunk = blockIdx.x;
    const int i = blockIdx.y;
    const int bb = blockIdx.z;
    const int t0 = tchunk * TCH;
    const int tid = threadIdx.x;
    const int lane = tid & 63;
    const int w = tid >> 6;        // wave 0..7
    const int r16 = lane & 15;
    const int g = lane >> 4;       // k-octet 0..3

    // ---- stage x tile via global_load_lds, inverse-swizzled source ----
    {
        const ushortT* gbase = xt + ((size_t)bb * TSZ + t0) * DIM;
        #pragma unroll
        for (int p = 0; p < 8; ++p) {
            const int chunk = p * 512 + tid;          // 16B chunk index, 0..4095
            const int row = chunk >> 6;               // t row 0..63
            const int cl = chunk & 63;                // physical chunk-in-row
            const int csrc = cl ^ (row & 7);          // logical source chunk
            __builtin_amdgcn_global_load_lds(
                (const __attribute__((address_space(1))) uintT*)(gbase + (size_t)row * DIM + csrc * 8),
                (__attribute__((address_space(3))) uintT*)(&xs[chunk * 8]), 16, 0, 0);
        }
    }
    __syncthreads();

    // ---- GEMM: xp[c][t] = sum_d Wco[i][c][d] * x[t][d]; wave w owns c-range w*64 ----
    f32x4 acc[4][4] = {};  // [t-tile][c-tile]
    const ushortT* wbase = Wco + (size_t)i * DIM * DIM + (size_t)(w * 64 + r16) * DIM + 8 * g;
    #pragma unroll 2
    for (int kt = 0; kt < 16; ++kt) {
        short8v bfr[4];
        #pragma unroll
        for (int tt = 0; tt < 4; ++tt) {
            const int row = tt * 16 + r16;
            bfr[tt] = *(const short8v*)(&xs[row * DIM + (((kt * 4 + g) ^ (row & 7)) << 3)]);
        }
        #pragma unroll
        for (int cc = 0; cc < 4; ++cc) {
            const short8v af = *(const short8v*)(wbase + (size_t)cc * 16 * DIM + kt * 32);
            #pragma unroll
            for (int tt = 0; tt < 4; ++tt)
                acc[tt][cc] = __builtin_amdgcn_mfma_f32_16x16x32_bf16(af, bfr[tt], acc[tt][cc], 0, 0, 0);
        }
    }
    __syncthreads();  // all xs reads complete before overwrite

    // ---- epilogue: + bias, bf16, write xp tile into xs (swizzled) ----
    #pragma unroll
    for (int cc = 0; cc < 4; ++cc) {
        const int c0 = w * 64 + cc * 16 + 4 * g;      // C-row = c = c0 + reg
        const float4 bv = *(const float4*)(bias + c0);
        #pragma unroll
        for (int tt = 0; tt < 4; ++tt) {
            const f32x4 v = acc[tt][cc];
            ushort4 h;
            h.x = f2bf(v[0] + bv.x);
            h.y = f2bf(v[1] + bv.y);
            h.z = f2bf(v[2] + bv.z);
            h.w = f2bf(v[3] + bv.w);
            const int tloc = tt * 16 + r16;           // C-col = t
            const int pchunk = ((c0 >> 3) ^ (tloc & 7));
            *(ushort4*)(&xs[tloc * DIM + (pchunk << 3) + (g & 1) * 4]) = h;
        }
    }
    __syncthreads();

    // ---- step C: predictions via diagonal MFMA ----
    const int off = i + 1;
    const int tlim = TSZ - off;
    const size_t segoff = 88ull * (2047ull * (size_t)i - (size_t)(i * (i - 1)) / 2);
    const int tt = w & 3;                 // t-tile 0..3
    const int t00 = tt * 16;
    const int nbase = (w >> 2) * 6;       // waves 0-3: n 0..5; waves 4-7: n 6..10
    const int ncnt = (w >> 2) ? 5 : 6;
    const int arow = t00 + r16;           // A-side local t row this lane loads
    const int tb = t0 + t00 + r16;        // B-side global t this lane gathers
    const int tauc = min(tb + off, TSZ - 1);
    const bool diag = (g == (r16 >> 2));  // lane holds C[r16][r16] in reg (r16&3)
    const int treg = r16 & 3;

    for (int nj = 0; nj < ncnt; ++nj) {
        const int n = nbase + nj;
        const int col = (n == 0) ? (bb * TSZ + tauc)
                                 : neg[bb * (NNEG * TSZ) + (n - 1) * TSZ + tauc];
        const ushortT* bptr = yt + (size_t)col * DIM + g * 8;
        f32x4 pacc = {};
        #pragma unroll 4
        for (int kt = 0; kt < 16; ++kt) {
            const short8v bf = *(const short8v*)(bptr + kt * 32);
            const short8v af = *(const short8v*)(&xs[arow * DIM + (((kt * 4 + g) ^ (arow & 7)) << 3)]);
            pacc = __builtin_amdgcn_mfma_f32_16x16x32_bf16(af, bf, pacc, 0, 0, 0);
        }
        if (diag && tb < tlim) {
            const float v01 = (treg & 1) ? pacc[1] : pacc[0];
            const float v23 = (treg & 1) ? pacc[3] : pacc[2];
            const float v = (treg & 2) ? v23 : v01;
            out[segoff + ((size_t)tb * BSZ + bb) * COPIES + n] = v;
        }
    }
}

__global__ __launch_bounds__(256) void labels_kernel(float* __restrict__ out) {
    const int idx = blockIdx.x * 256 + threadIdx.x;
    if (idx < 195984) out[2155824 + idx] = 0.0f;
}

extern "C" void kernel_launch(void* const* d_in, const int* in_sizes, int n_in,
                              void* d_out, int out_size, void* d_ws, size_t ws_size,
                              hipStream_t stream) {
    const float* x = (const float*)d_in[0];
    const float* y = (const float*)d_in[1];
    const float* W = (const float*)d_in[2];
    const float* b = (const float*)d_in[3];
    const int* neg = (const int*)d_in[4];
    float* out = (float*)d_out;
    ushortT* xt = (ushortT*)d_ws;
    ushortT* yt = (ushortT*)((char*)d_ws + 16777216);
    ushortT* Wco = (ushortT*)((char*)d_ws + 33554432);

    transpose_xy_kernel<<<dim3(TSZ / 32, DIM / 32, 16), dim3(32, 32), 0, stream>>>(x, y, xt, yt);
    transpose_w_kernel<<<dim3(DIM), dim3(256), 0, stream>>>(W, Wco);
    fused_kernel<<<dim3(TSZ / TCH, STEPS, BSZ), dim3(512), 0, stream>>>(xt, yt, Wco, b, neg, out);
    labels_kernel<<<dim3(766), dim3(256), 0, stream>>>(out);
}